// Round 16
// baseline (81.990 us; speedup 1.0000x reference)
//
#include <hip/hip_runtime.h>
#include <stdint.h>

#define BS   16384
#define XRW  768
#define HD   256
#define DIN  1280
#define N4   1024
#define NKT  40   // 1280 / 32 K-tiles (BK=32)

typedef __attribute__((ext_vector_type(4))) float f32x4;
typedef __attribute__((ext_vector_type(8))) short s16x8;
typedef __attribute__((ext_vector_type(4))) unsigned int u32x4;

__device__ __forceinline__ unsigned short f2bf(float f) {
  uint32_t u = __builtin_bit_cast(uint32_t, f);
  u += 0x7FFFu + ((u >> 16) & 1u);   // RNE
  return (unsigned short)(u >> 16);
}
__device__ __forceinline__ uint32_t cvtpk(float a, float b) {
  uint32_t d;
  asm("v_cvt_pk_bf16_f32 %0, %1, %2" : "=v"(d) : "v"(a), "v"(b));
  return d;
}
__device__ __forceinline__ float sigmoidf_(float x) {
  return 1.0f / (1.0f + __expf(-x));
}
__device__ __forceinline__ float tanhf_(float x) {
  return 1.0f - 2.0f / (__expf(2.0f * x) + 1.0f);
}
__device__ __forceinline__ void gload16(const void* g, void* l) {
  __builtin_amdgcn_global_load_lds((const __attribute__((address_space(1))) void*)g,
                                   (__attribute__((address_space(3))) void*)l, 16, 0, 0);
}

// ---- Wt[n'][k] bf16 row-major; n' = (h>>4)*64 + g*16 + (h&15).
// LDS-tiled transpose (R13, verified): b = g + 4*(kt + 20*ht).
__global__ __launch_bounds__(256) void conv_w_kernel(const float* __restrict__ Wi,
                                                     const float* __restrict__ Wf,
                                                     const float* __restrict__ Wo,
                                                     const float* __restrict__ Ws,
                                                     unsigned short* __restrict__ Wt) {
  __shared__ float tile[64][65];
  const int b  = blockIdx.x;
  const int g  = b & 3;
  const int t  = b >> 2;                // [0,80)
  const int k0 = (t % 20) * 64;
  const int h0 = (t / 20) * 64;
  const float* W = (g == 0) ? Wi : (g == 1) ? Wf : (g == 2) ? Wo : Ws;

  const int tr = threadIdx.x >> 4;
  const int tc = (threadIdx.x & 15) * 4;
  #pragma unroll
  for (int rr = 0; rr < 4; ++rr) {
    const int r = rr * 16 + tr;
    f32x4 v = *(const f32x4*)(W + (size_t)(k0 + r) * HD + h0 + tc);
    tile[r][tc + 0] = v.x; tile[r][tc + 1] = v.y;
    tile[r][tc + 2] = v.z; tile[r][tc + 3] = v.w;
  }
  __syncthreads();

  const int hl = threadIdx.x >> 2;
  const int kc = (threadIdx.x & 3) * 16;
  const int h  = h0 + hl;
  const int np = (h >> 4) * 64 + g * 16 + (h & 15);
  s16x8 o0, o1;
  #pragma unroll
  for (int j = 0; j < 8; ++j) {
    o0[j] = (short)f2bf(tile[kc + j][hl]);
    o1[j] = (short)f2bf(tile[kc + 8 + j][hl]);
  }
  *(s16x8*)(Wt + (size_t)np * DIN + k0 + kc)     = o0;
  *(s16x8*)(Wt + (size_t)np * DIN + k0 + kc + 8) = o1;
}

// ---- 256x128 tile, BK=32, 4 waves (2M x 2N -> wave 128x64, champion ILP),
// LDS 48KB (A 2x16K @0, B 2x8K @32K) + regs ~236 -> 2 RESIDENT BLOCKS/CU:
// two out-of-phase barrier domains fill each other's sync holes (m114),
// with the champion's per-tile rhythm preserved (issue-early A regs, async
// B gload_lds, counted VMW(2)/VMW(0), 1 barrier + publish-lgkm0 per tile).
// 64B LDS rows, (row>>1)&3 16B-unit XOR swizzle (bank-uniform, verified).
__global__ __launch_bounds__(256, 2)
void lstm_gemm_kernel(const float* __restrict__ X,
                      const float* __restrict__ PT,
                      const float* __restrict__ PL,
                      const unsigned short* __restrict__ Wt,
                      const float* __restrict__ BI,
                      const float* __restrict__ BF,
                      const float* __restrict__ BO,
                      const float* __restrict__ BSv,
                      const float* __restrict__ OLD,
                      float* __restrict__ out) {
  __shared__ unsigned char smem[49152];   // A: 2x16K @0; B: 2x8K @32K
  const int tid  = threadIdx.x;
  const int wid  = tid >> 6;
  const int lane = tid & 63;

  // T1: XCD owns 8 contiguous M-panels x all 8 N-tiles (512 = 8 x 64);
  // consecutive slots share mt -> co-resident block pairs share the A panel.
  const int H = blockIdx.x;
  const int xcd = H & 7, slot = H >> 3;          // slot in [0,64)
  const int mt = xcd * 8 + (slot >> 3);          // [0,64) 256-row panels
  const int nt = slot & 7;                       // [0,8)  128-col panels
  const int wr = wid >> 1, wc = wid & 1;

  // ---- B staging (gload_lds, linear LDS dest, pre-swizzled source col)
  const int bscol = ((tid & 3) ^ ((tid >> 3) & 3)) << 4;
  const char* gB = (const char*)Wt + (size_t)(nt * 128 + (tid >> 2)) * (DIN * 2) + bscol;

#define STAGE_B(t1, oB) do {                                                  \
    _Pragma("unroll")                                                         \
    for (int c_ = 0; c_ < 2; ++c_)                                            \
      gload16(gB + (size_t)c_ * (64 * DIN * 2) + (t1) * 64,                   \
              &smem[32768 + (oB) + c_ * 4096 + tid * 16]);                    \
  } while (0)

  // ---- A reg staging: thread covers row (tid>>1) of half h, 16 f32 of k
  const int arow_ = tid >> 1;                    // 0..127 (row within half)
  const int ak    = (tid & 1) * 16;              // k sub-offset (floats)
  const int as_   = (tid >> 2) & 3;              // swizzle s(row) = (row>>1)&3
  const int au0   = (tid & 1) * 2;               // logical 16B unit
  const int aw0   = (au0 ^ as_) << 4;            // phys byte offsets
  const int aw1   = ((au0 + 1) ^ as_) << 4;

#define ALOAD(t1, h, R0, R1, R2, R3) do {                                     \
    const float* asrc_; int astr_, aoff_;                                     \
    if ((t1) < 24)      { asrc_ = X;  astr_ = XRW; aoff_ = (t1) * 32; }       \
    else if ((t1) < 32) { asrc_ = PT; astr_ = HD;  aoff_ = ((t1) - 24) * 32; }\
    else                { asrc_ = PL; astr_ = HD;  aoff_ = ((t1) - 32) * 32; }\
    const float* ga_ = asrc_ + (size_t)(mt * 256 + arow_ + (h) * 128) * astr_ \
                             + aoff_ + ak;                                    \
    R0 = *(const f32x4*)(ga_);                                                \
    R1 = *(const f32x4*)(ga_ + 4);                                            \
    R2 = *(const f32x4*)(ga_ + 8);                                            \
    R3 = *(const f32x4*)(ga_ + 12);                                           \
  } while (0)

#define AWRITE(oA, h, R0, R1, R2, R3) do {                                    \
    u32x4 wlo_, whi_;                                                         \
    wlo_.x = cvtpk(R0.x, R0.y); wlo_.y = cvtpk(R0.z, R0.w);                   \
    wlo_.z = cvtpk(R1.x, R1.y); wlo_.w = cvtpk(R1.z, R1.w);                   \
    whi_.x = cvtpk(R2.x, R2.y); whi_.y = cvtpk(R2.z, R2.w);                   \
    whi_.z = cvtpk(R3.x, R3.y); whi_.w = cvtpk(R3.z, R3.w);                   \
    const int rb_ = (oA) + ((arow_ + (h) * 128) << 6);                        \
    *(u32x4*)(&smem[rb_ + aw0]) = wlo_;                                       \
    *(u32x4*)(&smem[rb_ + aw1]) = whi_;                                       \
  } while (0)

  // ---- frag read addressing (swizzle lane-invariant across mf/nf)
  const int rx   = lane & 15;
  const int colq = ((lane >> 4) ^ ((rx >> 1) & 3)) << 4;
  const int aRow = (wr * 128 + rx) * 64;               // + aBuf + mf*1024
  const int bRow = 32768 + (wc * 64 + rx) * 64;        // + bBuf + nf*1024

  f32x4 acc[8][4];
  #pragma unroll
  for (int i = 0; i < 8; ++i)
    #pragma unroll
    for (int j = 0; j < 4; ++j) {
      f32x4 z = {0.0f, 0.0f, 0.0f, 0.0f};
      acc[i][j] = z;
    }

#define VMW(N) asm volatile("s_waitcnt vmcnt(" #N ")" ::: "memory")
#define LGKM0() do { asm volatile("s_waitcnt lgkmcnt(0)" ::: "memory");       \
                     __builtin_amdgcn_sched_barrier(0); } while (0)
#define FRAGS(aB, bB) do {                                                    \
    _Pragma("unroll")                                                         \
    for (int nf = 0; nf < 4; ++nf)                                            \
      bq[nf] = *(const s16x8*)(&smem[(bB) + bRow + nf * 1024 + colq]);        \
    _Pragma("unroll")                                                         \
    for (int mf = 0; mf < 8; ++mf)                                            \
      aq[mf] = *(const s16x8*)(&smem[(aB) + aRow + mf * 1024 + colq]);        \
  } while (0)
#define MFH(m0_) do {                                                         \
    __builtin_amdgcn_s_setprio(1);                                            \
    _Pragma("unroll")                                                         \
    for (int mf = (m0_); mf < (m0_) + 4; ++mf)                                \
      _Pragma("unroll")                                                       \
      for (int nf = 0; nf < 4; ++nf)                                          \
        acc[mf][nf] = __builtin_amdgcn_mfma_f32_16x16x32_bf16(aq[mf], bq[nf], \
                                                      acc[mf][nf], 0, 0, 0);  \
    __builtin_amdgcn_s_setprio(0);                                            \
  } while (0)

  // ---- prologue: fill buf0 (A via regs+cvt, B via gload_lds)
  {
    f32x4 p0, p1, p2, p3;
    ALOAD(0, 0, p0, p1, p2, p3);
    STAGE_B(0, 0);
    VMW(2);        // A-H0 regs landed (B(0)'s 2 still flying)
    AWRITE(0, 0, p0, p1, p2, p3);
    ALOAD(0, 1, p0, p1, p2, p3);
    VMW(0);        // A-H1 + B(0) landed
    AWRITE(0, 1, p0, p1, p2, p3);
    LGKM0();
    __builtin_amdgcn_s_barrier();
  }

  for (int kt = 0; kt < NKT; ++kt) {
    const int aB = (kt & 1) << 14, aO = aB ^ 16384;
    const int bB = (kt & 1) << 13, bO = bB ^ 8192;
    const bool pf = (kt + 1) < NKT;
    s16x8 aq[8], bq[4];
    f32x4 ar0, ar1, ar2, ar3;

    if (pf) ALOAD(kt + 1, 0, ar0, ar1, ar2, ar3);   // issue-early: A(k+1) H0
    FRAGS(aB, bB);
    if (pf) STAGE_B(kt + 1, bO);                    // B(k+1) -> LDS (async)
    MFH(0);                                         // unpinned: reads pipeline in
    VMW(2);                                         // A-H0 regs landed
    if (pf) { AWRITE(aO, 0, ar0, ar1, ar2, ar3); ALOAD(kt + 1, 1, ar0, ar1, ar2, ar3); }
    MFH(4);
    VMW(0);                                         // A-H1 regs + B(k+1) in LDS
    if (pf) AWRITE(aO, 1, ar0, ar1, ar2, ar3);
    LGKM0();                                        // publish my ds_writes
    __builtin_amdgcn_s_barrier();                   // next tile's bufs ready
  }

  // ---- pure-register epilogue (R15): OLD pipelined one mf ahead; NT stores.
  {
    const int hq = (nt * 2 + wc) * 16 + rx;
    const float bbi = BI[hq], bbf = BF[hq], bbo = BO[hq], bbs = BSv[hq];
    const int m0 = mt * 256 + wr * 128 + (lane >> 4) * 4;
    float* outNS = out + (size_t)BS * HD;
    float oldc[4], oldn[4];
    #pragma unroll
    for (int r = 0; r < 4; ++r)
      oldc[r] = OLD[(size_t)(m0 + r) * HD + hq];
    #pragma unroll
    for (int mf = 0; mf < 8; ++mf) {
      const int mrow = m0 + mf * 16;
      if (mf < 7) {
        #pragma unroll
        for (int r = 0; r < 4; ++r)
          oldn[r] = OLD[(size_t)(mrow + 16 + r) * HD + hq];
      }
      #pragma unroll
      for (int r = 0; r < 4; ++r) {
        const float ig = sigmoidf_(acc[mf][0][r] + bbi);
        const float fg = sigmoidf_(acc[mf][1][r] + bbf);
        const float og = sigmoidf_(acc[mf][2][r] + bbo);
        const float cg = tanhf_(acc[mf][3][r] + bbs);
        const float ns = fg * oldc[r] + ig * cg;
        const float nh = og * tanhf_(ns);
        __builtin_nontemporal_store(nh, &out[(size_t)(mrow + r) * HD + hq]);
        __builtin_nontemporal_store(ns, &outNS[(size_t)(mrow + r) * HD + hq]);
      }
      #pragma unroll
      for (int r = 0; r < 4; ++r)
        oldc[r] = oldn[r];
    }
  }
#undef STAGE_B
#undef ALOAD
#undef AWRITE
#undef VMW
#undef LGKM0
#undef FRAGS
#undef MFH
}

extern "C" void kernel_launch(void* const* d_in, const int* in_sizes, int n_in,
                              void* d_out, int out_size, void* d_ws, size_t ws_size,
                              hipStream_t stream) {
  const float* X   = (const float*)d_in[0];
  const float* PT  = (const float*)d_in[1];
  const float* PL  = (const float*)d_in[2];
  const float* OLD = (const float*)d_in[3];
  const float* Wi  = (const float*)d_in[4];
  const float* bi  = (const float*)d_in[5];
  const float* Wf  = (const float*)d_in[6];
  const float* bfv = (const float*)d_in[7];
  const float* Wo  = (const float*)d_in[8];
  const float* bo  = (const float*)d_in[9];
  const float* Ws  = (const float*)d_in[10];
  const float* bsv = (const float*)d_in[11];
  float* out = (float*)d_out;

  unsigned short* Wt = (unsigned short*)d_ws;   // 1024*1280*2 = 2.62 MB

  conv_w_kernel<<<320, 256, 0, stream>>>(Wi, Wf, Wo, Ws, Wt);
  lstm_gemm_kernel<<<512, 256, 0, stream>>>(X, PT, PL, Wt, bi, bfv, bo, bsv, OLD, out);
}